// Round 1
// baseline (2689.107 us; speedup 1.0000x reference)
//
#include <hip/hip_runtime.h>
#include <hip/hip_cooperative_groups.h>

namespace cg = cooperative_groups;

#define K_ITER   30
#define MU       0.01f
#define EPS      1e-6f
#define MAX_LS   25
#define FULLMASK 0x01FFFFFFu
#define MM       128
#define NN       256

#define WAVE_RED_ADD(v) do { \
    v += __shfl_xor(v, 1);  v += __shfl_xor(v, 2);  v += __shfl_xor(v, 4); \
    v += __shfl_xor(v, 8);  v += __shfl_xor(v, 16); v += __shfl_xor(v, 32); } while (0)

__global__ __launch_bounds__(256, 2)
void lbp_kernel(const float* __restrict__ xraw_g,
                const float* __restrict__ A_g,
                const float* __restrict__ b_g,
                const float* __restrict__ lower_g,
                float* __restrict__ out_g,
                unsigned* __restrict__ gmask)
{
    const int p    = blockIdx.x;       // problem 0..511
    const int t    = threadIdx.x;      // 0..255
    const int lane = t & 63;
    const int wave = t >> 6;           // 0..3

    const float* A  = A_g    + (size_t)p * (MM * NN);
    const float* bb = b_g    + p * MM;
    const float* xr = xraw_g + p * NN;
    const float* lo = lower_g + p * NN;

    __shared__ __align__(16) float s_x[NN];
    __shared__ __align__(16) float s_grad[NN];
    __shared__ __align__(16) float s_xraw[NN];
    __shared__ __align__(16) float s_lower[NN];
    __shared__ float s_Ax[MM], s_Ag[MM], s_b[MM], s_c[MM], s_e2[MM];
    __shared__ float s_Ad[MM], s_Al[MM];
    __shared__ float s_red[256];
    __shared__ unsigned s_mask;

    cg::grid_group grid = cg::this_grid();

    // ---- init global masks (block 0), consumed only after grid.sync #0 ----
    if (p == 0 && t < K_ITER) gmask[t] = FULLMASK;

    // ---- load small vectors ----
    s_xraw[t]  = xr[t];
    s_lower[t] = lo[t];
    if (t < MM) s_b[t] = bb[t];

    // ---- row stats: ssq (-> row norm), rowsum (Ad), A·lower ----
    {
        const float4 lo4 = ((const float4*)lo)[lane];   // from global, no LDS dep
        for (int i = 0; i < 32; ++i) {
            const int m = wave * 32 + i;
            const float4 a4 = ((const float4*)(A + m * NN))[lane];
            float ssq = a4.x*a4.x + a4.y*a4.y + a4.z*a4.z + a4.w*a4.w;
            float rs  = a4.x + a4.y + a4.z + a4.w;
            float al  = a4.x*lo4.x + a4.y*lo4.y + a4.z*lo4.z + a4.w*lo4.w;
            WAVE_RED_ADD(ssq); WAVE_RED_ADD(rs); WAVE_RED_ADD(al);
            if (lane == 0) { s_Ag[m] = ssq; s_Ad[m] = rs; s_Al[m] = al; }
        }
    }
    __syncthreads();

    // ---- per-row derived quantities + Chebyshev-ish interior init ----
    if (t < MM) {
        const float r   = fmaxf(sqrtf(s_Ag[t]), 1e-12f);   // row_norm
        s_c[t]  = s_b[t] - EPS * r;       // feasibility threshold (unnormalized)
        s_e2[t] = 1e-12f * r;             // slack clamp (unnormalized)
        const float adw = s_Ad[t] / r;    // normalized rowsum
        const float sw  = (s_b[t] - s_Al[t]) / r;
        s_red[t] = (adw > 0.f) ? (sw / fmaxf(adw, 1e-12f)) : INFINITY;
    } else {
        s_red[t] = INFINITY;
    }
    __syncthreads();
    for (int s = 128; s > 0; s >>= 1) {
        if (t < s) s_red[t] = fminf(s_red[t], s_red[t + s]);
        __syncthreads();
    }
    const float t0 = fmaxf(0.5f * s_red[0], 2.0f * EPS);

    s_x[t] = s_lower[t] + t0;
    if (t < MM) s_Ax[t] = s_Al[t] + t0 * s_Ad[t];
    __syncthreads();

    // ---- feasibility repair branch (faithful; no-op for these inputs) ----
    {
        const int condA = (t < MM) ? (s_Ax[t] <= s_c[t]) : 1;
        const int condB = (s_x[t] >= s_lower[t] + EPS) ? 1 : 0;
        const int feas  = __syncthreads_and(condA && condB);
        if (!feas) {
            s_x[t] = 0.5f * (fmaxf(s_x[t], 0.f) + s_lower[t]);
            __syncthreads();
            const float4 x4 = ((const float4*)s_x)[lane];
            for (int i = 0; i < 32; ++i) {
                const int m = wave * 32 + i;
                const float4 a4 = ((const float4*)(A + m * NN))[lane];
                float px = a4.x*x4.x + a4.y*x4.y + a4.z*x4.z + a4.w*x4.w;
                WAVE_RED_ADD(px);
                if (lane == 0) s_Ax[m] = px;
            }
            __syncthreads();
        }
    }

    grid.sync();   // gmask init visible; everyone past init

    const float mystep = (lane < MAX_LS) ? ldexpf(1.0f, -lane) : 0.0f;

    for (int k = 0; k < K_ITER; ++k) {
        // -- barrier weights w_m = MU / max(b - Ax, 1e-12*r)  (stored in s_Ad) --
        if (t < MM) s_Ad[t] = MU / fmaxf(s_b[t] - s_Ax[t], s_e2[t]);
        if (t == 255) s_mask = 0xFFFFFFFFu;
        __syncthreads();

        // -- pass 1: g_bar_n = sum_m A[m][n] * w_m  (coalesced, thread-per-col) --
        float g = 0.f;
        #pragma unroll 8
        for (int m = 0; m < MM; ++m) g = fmaf(A[m * NN + t], s_Ad[m], g);

        const float xt  = s_x[t];
        const float gr  = (xt - s_xraw[t]) + g + MU / fmaxf(xt - s_lower[t], 1e-12f);
        s_grad[t] = gr;

        // n-side line-search mask: bit l set iff x - step_l*grad >= lower+EPS
        {
            unsigned mn = 0u;
            const float loe = s_lower[t] + EPS;
            float st = 1.0f;
            #pragma unroll
            for (int l = 0; l < MAX_LS; ++l) {
                if (xt - st * gr >= loe) mn |= (1u << l);
                st *= 0.5f;
            }
            mn &= __shfl_xor(mn, 1);  mn &= __shfl_xor(mn, 2);
            mn &= __shfl_xor(mn, 4);  mn &= __shfl_xor(mn, 8);
            mn &= __shfl_xor(mn, 16); mn &= __shfl_xor(mn, 32);
            if (lane == 0) atomicAnd(&s_mask, mn);
        }
        __syncthreads();   // s_grad complete

        // -- pass 2: Ag = A*grad and fresh Ax = A*x (wave-per-row, float4) --
        {
            const float4 g4 = ((const float4*)s_grad)[lane];
            const float4 x4 = ((const float4*)s_x)[lane];
            unsigned mm = 0xFFFFFFFFu;
            for (int i = 0; i < 32; ++i) {
                const int m = wave * 32 + i;
                const float4 a4 = ((const float4*)(A + m * NN))[lane];
                float pg = a4.x*g4.x + a4.y*g4.y + a4.z*g4.z + a4.w*g4.w;
                float px = a4.x*x4.x + a4.y*x4.y + a4.z*x4.z + a4.w*x4.w;
                WAVE_RED_ADD(pg); WAVE_RED_ADD(px);   // all lanes get totals
                bool okm = true;
                if (lane < MAX_LS) okm = (px - mystep * pg) <= s_c[m];
                const unsigned long long bal = __ballot(okm);
                mm &= ((unsigned)bal | ~FULLMASK);
                if (lane == 0) { s_Ag[m] = pg; s_Ax[m] = px; }
            }
            if (lane == 0) atomicAnd(&s_mask, mm);
        }
        __syncthreads();

        if (t == 0) atomicAnd(&gmask[k], s_mask & FULLMASK);
        grid.sync();   // global AND complete

        const unsigned gm = ((volatile unsigned*)gmask)[k];
        const float step = gm ? ldexpf(1.0f, -(__ffs(gm) - 1)) : 0.0f;
        s_x[t] = xt - step * gr;
        if (t < MM) s_Ax[t] = s_Ax[t] - step * s_Ag[t];
        __syncthreads();
    }

    out_g[p * NN + t] = fmaxf(s_x[t], 0.0f);
}

extern "C" void kernel_launch(void* const* d_in, const int* in_sizes, int n_in,
                              void* d_out, int out_size, void* d_ws, size_t ws_size,
                              hipStream_t stream) {
    const float* xraw  = (const float*)d_in[0];
    const float* A     = (const float*)d_in[1];
    const float* b     = (const float*)d_in[2];
    const float* lower = (const float*)d_in[3];
    float* out = (float*)d_out;
    unsigned* gmask = (unsigned*)d_ws;

    void* args[] = { (void*)&xraw, (void*)&A, (void*)&b, (void*)&lower,
                     (void*)&out, (void*)&gmask };
    hipLaunchCooperativeKernel((const void*)lbp_kernel, dim3(512), dim3(256),
                               args, 0, stream);
}

// Round 2
// 851.097 us; speedup vs baseline: 3.1596x; 3.1596x over previous
//
#include <hip/hip_runtime.h>

#define K_ITER   30
#define MU       0.01f
#define EPS      1e-6f
#define MAX_LS   25
#define FULLMASK 0x01FFFFFFu
#define MM       128
#define NN       256
#define NPROB    512

// ws layout (floats)
#define OX   ((size_t)0)                    // x        [NPROB*NN]
#define OG   ((size_t)(NPROB*NN))           // grad     [NPROB*NN]
#define OAX  ((size_t)(2*NPROB*NN))         // Ax       [NPROB*MM]
#define OAG  (OAX + (size_t)(NPROB*MM))     // Ag       [NPROB*MM]
#define OR_  (OAG + (size_t)(NPROB*MM))     // rownorm  [NPROB*MM]
#define OEND (OR_ + (size_t)(NPROB*MM))     // gmask (unsigned[32]) lives here

#define WAVE_RED_ADD(v) do { \
    v += __shfl_xor(v, 1);  v += __shfl_xor(v, 2);  v += __shfl_xor(v, 4); \
    v += __shfl_xor(v, 8);  v += __shfl_xor(v, 16); v += __shfl_xor(v, 32); } while (0)

// ---------------------------------------------------------------- init ----
__global__ __launch_bounds__(1024, 8)
void lbp_init(const float* __restrict__ A_g,
              const float* __restrict__ b_g,
              const float* __restrict__ lower_g,
              float* __restrict__ ws,
              unsigned* __restrict__ gmask)
{
    const int p    = blockIdx.x;
    const int t    = threadIdx.x;
    const int lane = t & 63;
    const int wave = t >> 6;           // 0..15

    const float* A  = A_g + (size_t)p * (MM * NN);
    const float* bb = b_g + p * MM;

    __shared__ __align__(16) float s_lower[NN];
    __shared__ __align__(16) float s_x[NN];
    __shared__ float s_ssq[MM], s_rs[MM], s_al[MM];
    __shared__ float s_red[MM];
    __shared__ float s_t0;

    if (t < NN) s_lower[t] = lower_g[p * NN + t];
    __syncthreads();

    // row stats: ssq, rowsum, A·lower  (8 rows per wave)
    {
        const float4 lo4 = ((const float4*)s_lower)[lane];
        #pragma unroll 2
        for (int i = 0; i < 8; ++i) {
            const int m = wave * 8 + i;
            const float4 a4 = ((const float4*)(A + m * NN))[lane];
            float ssq = a4.x*a4.x + a4.y*a4.y + a4.z*a4.z + a4.w*a4.w;
            float rs  = a4.x + a4.y + a4.z + a4.w;
            float al  = a4.x*lo4.x + a4.y*lo4.y + a4.z*lo4.z + a4.w*lo4.w;
            WAVE_RED_ADD(ssq); WAVE_RED_ADD(rs); WAVE_RED_ADD(al);
            if (lane == 0) { s_ssq[m] = ssq; s_rs[m] = rs; s_al[m] = al; }
        }
    }
    __syncthreads();

    if (t < MM) {
        const float r = fmaxf(sqrtf(s_ssq[t]), 1e-12f);
        s_ssq[t] = r;                          // keep r for later
        ws[OR_ + p * MM + t] = r;
        const float adw = s_rs[t] / r;
        const float sw  = (bb[t] - s_al[t]) / r;
        s_red[t] = (adw > 0.f) ? (sw / fmaxf(adw, 1e-12f)) : INFINITY;
    }
    __syncthreads();
    if (t < 64) s_red[t] = fminf(s_red[t], s_red[t + 64]);
    __syncthreads();
    if (t < 32) s_red[t] = fminf(s_red[t], s_red[t + 32]);
    __syncthreads();
    if (t < 16) s_red[t] = fminf(s_red[t], s_red[t + 16]);
    __syncthreads();
    if (t < 8)  s_red[t] = fminf(s_red[t], s_red[t + 8]);
    __syncthreads();
    if (t < 4)  s_red[t] = fminf(s_red[t], s_red[t + 4]);
    __syncthreads();
    if (t == 0) s_t0 = fmaxf(0.5f * fminf(fminf(s_red[0], s_red[1]),
                                          fminf(s_red[2], s_red[3])), 2.0f * EPS);
    __syncthreads();
    const float t0 = s_t0;

    float x = 0.f, ax = 0.f;
    if (t < NN) x  = s_lower[t] + t0;
    if (t < MM) ax = s_al[t] + t0 * s_rs[t];

    // feasibility repair (faithful to module; no-op for these inputs)
    int ok = 1;
    if (t < MM) ok = ok && (ax <= bb[t] - EPS * s_ssq[t]);
    if (t < NN) ok = ok && (x >= s_lower[t] + EPS);
    const int feas = __syncthreads_and(ok);
    if (!feas) {
        if (t < NN) { x = 0.5f * (fmaxf(x, 0.f) + s_lower[t]); s_x[t] = x; }
        __syncthreads();
        const float4 x4 = ((const float4*)s_x)[lane];
        for (int i = 0; i < 8; ++i) {
            const int m = wave * 8 + i;
            const float4 a4 = ((const float4*)(A + m * NN))[lane];
            float px = a4.x*x4.x + a4.y*x4.y + a4.z*x4.z + a4.w*x4.w;
            WAVE_RED_ADD(px);
            if (lane == 0) s_al[m] = px;
        }
        __syncthreads();
        if (t < MM) ax = s_al[t];
    }

    if (t < NN) ws[OX  + p * NN + t] = x;
    if (t < MM) ws[OAX + p * MM + t] = ax;
    if (p == 0 && t < K_ITER) gmask[t] = FULLMASK;
}

// ---------------------------------------------------------------- iter ----
__global__ __launch_bounds__(1024, 8)
void lbp_iter(const float* __restrict__ A_g,
              const float* __restrict__ b_g,
              const float* __restrict__ xraw_g,
              const float* __restrict__ lower_g,
              float* __restrict__ ws,
              unsigned* __restrict__ gmask,
              int k)
{
    const int p    = blockIdx.x;
    const int t    = threadIdx.x;
    const int lane = t & 63;
    const int wave = t >> 6;           // 0..15

    const float* A  = A_g + (size_t)p * (MM * NN);
    const float* bb = b_g + p * MM;

    __shared__ __align__(16) float s_x[NN];
    __shared__ __align__(16) float s_grad[NN];
    __shared__ __align__(16) float s_xraw[NN];
    __shared__ __align__(16) float s_lower[NN];
    __shared__ float s_w[MM], s_c[MM];
    __shared__ float s_part[4][NN];
    __shared__ unsigned s_mask;

    if (t == 0) s_mask = 0xFFFFFFFFu;
    if (t < NN) { s_xraw[t] = xraw_g[p * NN + t]; s_lower[t] = lower_g[p * NN + t]; }

    float step = 0.f;
    if (k > 0) {
        const unsigned gm = gmask[k - 1];
        step = gm ? ldexpf(1.0f, -(__ffs(gm) - 1)) : 0.0f;
    }
    if (t < NN) {
        float x = ws[OX + p * NN + t];
        if (k > 0) { x -= step * ws[OG + p * NN + t]; ws[OX + p * NN + t] = x; }
        s_x[t] = x;
    }
    if (t < MM) {
        float ax = ws[OAX + p * MM + t];
        if (k > 0) ax -= step * ws[OAG + p * MM + t];
        const float r  = ws[OR_ + p * MM + t];
        const float bm = bb[t];
        s_c[t] = bm - EPS * r;                         // unnormalized threshold
        s_w[t] = MU / fmaxf(bm - ax, 1e-12f * r);      // barrier weight
    }
    __syncthreads();

    // pass 1: g_bar = A^T w  — 4-way row split, thread-per-column
    {
        const int col = t & (NN - 1);
        const int q   = t >> 8;                        // 0..3 (rows q*32..+31)
        const float* Ac = A + (size_t)(q * 32) * NN + col;
        float g = 0.f;
        #pragma unroll 8
        for (int j = 0; j < 32; ++j) g = fmaf(Ac[(size_t)j * NN], s_w[q * 32 + j], g);
        s_part[q][col] = g;
    }
    __syncthreads();

    if (t < NN) {
        const float g  = s_part[0][t] + s_part[1][t] + s_part[2][t] + s_part[3][t];
        const float xt = s_x[t];
        const float gr = (xt - s_xraw[t]) + g + MU / fmaxf(xt - s_lower[t], 1e-12f);
        s_grad[t] = gr;
        ws[OG + p * NN + t] = gr;

        // n-side line-search mask: bit l set iff x - step_l*grad >= lower+EPS
        unsigned mn = 0u;
        const float loe = s_lower[t] + EPS;
        float st = 1.0f;
        #pragma unroll
        for (int l = 0; l < MAX_LS; ++l) {
            if (xt - st * gr >= loe) mn |= (1u << l);
            st *= 0.5f;
        }
        mn &= __shfl_xor(mn, 1);  mn &= __shfl_xor(mn, 2);
        mn &= __shfl_xor(mn, 4);  mn &= __shfl_xor(mn, 8);
        mn &= __shfl_xor(mn, 16); mn &= __shfl_xor(mn, 32);
        if (lane == 0) atomicAnd(&s_mask, mn);
    }
    __syncthreads();   // s_grad complete

    // pass 2: Ag = A*grad, fresh Ax = A*x  — 8 rows per wave
    {
        const float4 g4 = ((const float4*)s_grad)[lane];
        const float4 x4 = ((const float4*)s_x)[lane];
        const float mystep = (lane < MAX_LS) ? ldexpf(1.0f, -lane) : 0.0f;
        unsigned mm = 0xFFFFFFFFu;
        #pragma unroll 2
        for (int i = 0; i < 8; ++i) {
            const int m = wave * 8 + i;
            const float4 a4 = ((const float4*)(A + m * NN))[lane];
            float pg = a4.x*g4.x + a4.y*g4.y + a4.z*g4.z + a4.w*g4.w;
            float px = a4.x*x4.x + a4.y*x4.y + a4.z*x4.z + a4.w*x4.w;
            WAVE_RED_ADD(pg); WAVE_RED_ADD(px);
            bool okm = true;
            if (lane < MAX_LS) okm = (px - mystep * pg) <= s_c[m];
            const unsigned long long bal = __ballot(okm);
            mm &= ((unsigned)bal | ~FULLMASK);
            if (lane == 0) { ws[OAG + p * MM + m] = pg; ws[OAX + p * MM + m] = px; }
        }
        if (lane == 0) atomicAnd(&s_mask, mm);
    }
    __syncthreads();

    if (t == 0) atomicAnd(&gmask[k], s_mask & FULLMASK);
}

// ------------------------------------------------------------ finalize ----
__global__ __launch_bounds__(256)
void lbp_fin(const float* __restrict__ ws,
             const unsigned* __restrict__ gmask,
             float* __restrict__ out_g)
{
    const int p = blockIdx.x;
    const int t = threadIdx.x;
    const unsigned gm = gmask[K_ITER - 1];
    const float step = gm ? ldexpf(1.0f, -(__ffs(gm) - 1)) : 0.0f;
    const float x = ws[OX + p * NN + t] - step * ws[OG + p * NN + t];
    out_g[p * NN + t] = fmaxf(x, 0.0f);
}

// -------------------------------------------------------------- launch ----
extern "C" void kernel_launch(void* const* d_in, const int* in_sizes, int n_in,
                              void* d_out, int out_size, void* d_ws, size_t ws_size,
                              hipStream_t stream) {
    const float* xraw  = (const float*)d_in[0];
    const float* A     = (const float*)d_in[1];
    const float* b     = (const float*)d_in[2];
    const float* lower = (const float*)d_in[3];
    float* out = (float*)d_out;

    float* ws = (float*)d_ws;
    unsigned* gmask = (unsigned*)(ws + OEND);

    lbp_init<<<NPROB, 1024, 0, stream>>>(A, b, lower, ws, gmask);
    for (int k = 0; k < K_ITER; ++k)
        lbp_iter<<<NPROB, 1024, 0, stream>>>(A, b, xraw, lower, ws, gmask, k);
    lbp_fin<<<NPROB, 256, 0, stream>>>(ws, gmask, out);
}